// Round 7
// baseline (35.296 us; speedup 1.0000x reference)
//
#include <hip/hip_runtime.h>

// TV-like sum over interior 62x62 of each 64x64 image, edge-pair formulation:
//   vertical edge (i,i+1), col c in [1,62]: weight (i==0||i==62) ? 1 : 2
//   horizontal edge (c,c+1), row r in [1,62]: weight (c==0||c==62) ? 1 : 2
// Every element loaded exactly once. One 64-lane wave processes TWO images,
// all 32 float4 loads issued before compute -> 512B/lane in flight (MLP).
// Per image: lane-group l=w&15 owns cols 4l..4l+3, row-group g=w>>4 owns
// rows 16g..16g+15; boundary row 16g+16 via __shfl_down(v[0],16).
// Single compute dispatch: per-block reduce -> one f32 atomicAdd into out.
// Graph = [memset(out,4B), kernel].

__device__ __forceinline__ float tv_image(const float4 v[16], int r0,
                                          float vw0, float vw3,
                                          float hw0, float hw2, float hw3) {
    // Boundary row r0+16 == lane (w+16)'s v[0]; g==3 oob -> own value, weight 0.
    float4 b;
    b.x = __shfl_down(v[0].x, 16, 64);
    b.y = __shfl_down(v[0].y, 16, 64);
    b.z = __shfl_down(v[0].z, 16, 64);
    b.w = __shfl_down(v[0].w, 16, 64);

    float acc = 0.f;
#pragma unroll
    for (int rr = 0; rr < 16; ++rr) {
        const float4 cur = v[rr];
        const int hr = r0 + rr;
        const float hrow = (hr >= 1 && hr <= 62) ? 1.f : 0.f;
        const float nx = __shfl_down(cur.x, 1, 64);     // next lane's col c3+1
        acc += hrow * (hw0 * fabsf(cur.x - cur.y) + 2.f * fabsf(cur.y - cur.z)
                     + hw2 * fabsf(cur.z - cur.w) + hw3 * fabsf(cur.w - nx));
        const float4 nxt = (rr < 15) ? v[rr + 1] : b;
        const float wv = (hr == 0 || hr == 62) ? 1.f : (hr < 63 ? 2.f : 0.f);
        acc += wv * (vw0 * fabsf(cur.x - nxt.x) + fabsf(cur.y - nxt.y)
                   + fabsf(cur.z - nxt.z) + vw3 * fabsf(cur.w - nxt.w));
    }
    return acc;
}

__global__ __launch_bounds__(256, 3) void tv_fused(const float* __restrict__ fai,
                                                   float* __restrict__ out) {
    const int tid  = threadIdx.x;
    const int w    = tid & 63;
    const int wave = blockIdx.x * 4 + (tid >> 6);    // 4 waves/block
    const int l    = w & 15;                         // cols 4l..4l+3
    const int r0   = (w >> 4) * 16;                  // rows 16g..16g+15

    // Two consecutive images per wave (contiguous 32KB -> DRAM locality).
    const float4* a4 = (const float4*)(fai + (size_t)(2 * wave) * 4096) + r0 * 16 + l;
    const float4* b4 = a4 + 1024;                    // next image

    // Issue ALL 32 loads back-to-back before any use.
    float4 vA[16], vB[16];
#pragma unroll
    for (int rr = 0; rr < 16; ++rr) vA[rr] = a4[rr * 16];
#pragma unroll
    for (int rr = 0; rr < 16; ++rr) vB[rr] = b4[rr * 16];

    const int c0 = 4 * l, c2 = c0 + 2, c3 = c0 + 3;
    const float vw0 = (c0 >= 1) ? 1.f : 0.f;    // col 0 excluded (l==0)
    const float vw3 = (c3 <= 62) ? 1.f : 0.f;   // col 63 excluded (l==15)
    const float hw0 = (c0 == 0) ? 1.f : 2.f;
    const float hw2 = (c2 == 62) ? 1.f : 2.f;
    const float hw3 = (c3 <= 62) ? 2.f : 0.f;   // absent at l==15

    float acc = tv_image(vA, r0, vw0, vw3, hw0, hw2, hw3)
              + tv_image(vB, r0, vw0, vw3, hw0, hw2, hw3);

    // Wave(64) shuffle reduction.
#pragma unroll
    for (int off = 32; off > 0; off >>= 1) acc += __shfl_down(acc, off, 64);

    // Cross-wave reduction (4 waves), one atomic per block (1024 total).
    __shared__ float wsum[4];
    if (w == 0) wsum[tid >> 6] = acc;
    __syncthreads();
    if (tid == 0)
        atomicAdd(out, (wsum[0] + wsum[1]) + (wsum[2] + wsum[3]));
}

extern "C" void kernel_launch(void* const* d_in, const int* in_sizes, int n_in,
                              void* d_out, int out_size, void* d_ws, size_t ws_size,
                              hipStream_t stream) {
    const float* fai = (const float*)d_in[0];
    float* out = (float*)d_out;

    // out is poisoned once and not re-poisoned between replays; we accumulate
    // with atomics, so zero it every call (capture-safe 4B fill node).
    hipMemsetAsync(out, 0, sizeof(float), stream);

    const int n_blocks = 8192 / 8;              // 2 imgs/wave x 4 waves/block
    tv_fused<<<n_blocks, 256, 0, stream>>>(fai, out);
}

// Round 8
// 27.532 us; speedup vs baseline: 1.2820x; 1.2820x over previous
//
#include <hip/hip_runtime.h>

// TV-like sum over interior 62x62 of each 64x64 image, edge-pair formulation:
//   vertical edge (i,i+1), col c in [1,62]: weight (i==0||i==62) ? 1 : 2
//   horizontal edge (c,c+1), row r in [1,62]: weight (c==0||c==62) ? 1 : 2
// Every element loaded exactly once. One wave = TWO images; A's 16 loads
// issue first, B's loads interleave with A's compute (bounds live regs to
// ~20 float4 -> fits the 128-VGPR cap of __launch_bounds__(256,4), giving
// 4 blocks/CU resident -> 1024 blocks = ONE generation, no ragged tail).
// Two-stage reduction (no atomics, no memset): R7 showed ~1024 same-address
// atomics cost ~8us of serialized tail; two dispatches cost ~3us.

__device__ __forceinline__ float tv_rows(const float4& cur, const float4& nxt,
                                         int hr, float vw0, float vw3,
                                         float hw0, float hw2, float hw3) {
    float acc = 0.f;
    const float hrow = (hr >= 1 && hr <= 62) ? 1.f : 0.f;
    const float nx = __shfl_down(cur.x, 1, 64);          // next lane's col c3+1
    acc += hrow * (hw0 * fabsf(cur.x - cur.y) + 2.f * fabsf(cur.y - cur.z)
                 + hw2 * fabsf(cur.z - cur.w) + hw3 * fabsf(cur.w - nx));
    const float wv = (hr == 0 || hr == 62) ? 1.f : (hr < 63 ? 2.f : 0.f);
    acc += wv * (vw0 * fabsf(cur.x - nxt.x) + fabsf(cur.y - nxt.y)
               + fabsf(cur.z - nxt.z) + vw3 * fabsf(cur.w - nxt.w));
    return acc;
}

__global__ __launch_bounds__(256, 4) void tv_stage1(const float* __restrict__ fai,
                                                    float* __restrict__ partial) {
    const int tid  = threadIdx.x;
    const int w    = tid & 63;
    const int wave = blockIdx.x * 4 + (tid >> 6);    // 4 waves/block
    const int l    = w & 15;                         // cols 4l..4l+3
    const int r0   = (w >> 4) * 16;                  // rows 16g..16g+15

    // Two consecutive images per wave (contiguous 32KB).
    const float4* a4 = (const float4*)(fai + (size_t)(2 * wave) * 4096) + r0 * 16 + l;
    const float4* b4 = a4 + 1024;                    // next image

    const int c0 = 4 * l, c2 = c0 + 2, c3 = c0 + 3;
    const float vw0 = (c0 >= 1) ? 1.f : 0.f;    // col 0 excluded (l==0)
    const float vw3 = (c3 <= 62) ? 1.f : 0.f;   // col 63 excluded (l==15)
    const float hw0 = (c0 == 0) ? 1.f : 2.f;
    const float hw2 = (c2 == 62) ? 1.f : 2.f;
    const float hw3 = (c3 <= 62) ? 2.f : 0.f;   // absent at l==15

    // Phase 1: issue all 16 A loads.
    float4 vA[16];
#pragma unroll
    for (int rr = 0; rr < 16; ++rr) vA[rr] = a4[rr * 16];

    // A's boundary row (r0+16) = lane (w+16)'s vA[0]; g==3 oob -> weight 0.
    float4 bA;
    bA.x = __shfl_down(vA[0].x, 16, 64);
    bA.y = __shfl_down(vA[0].y, 16, 64);
    bA.z = __shfl_down(vA[0].z, 16, 64);
    bA.w = __shfl_down(vA[0].w, 16, 64);

    // Phase 2: interleave B-load issue with A-compute (caps live registers;
    // B latency hides under ~600 cycles of A arithmetic).
    float4 vB[16];
    float acc = 0.f;
#pragma unroll
    for (int rr = 0; rr < 16; ++rr) {
        vB[rr] = b4[rr * 16];
        const float4 nxt = (rr < 15) ? vA[rr + 1] : bA;
        acc += tv_rows(vA[rr], nxt, r0 + rr, vw0, vw3, hw0, hw2, hw3);
    }

    // Phase 3: compute B.
    float4 bB;
    bB.x = __shfl_down(vB[0].x, 16, 64);
    bB.y = __shfl_down(vB[0].y, 16, 64);
    bB.z = __shfl_down(vB[0].z, 16, 64);
    bB.w = __shfl_down(vB[0].w, 16, 64);
#pragma unroll
    for (int rr = 0; rr < 16; ++rr) {
        const float4 nxt = (rr < 15) ? vB[rr + 1] : bB;
        acc += tv_rows(vB[rr], nxt, r0 + rr, vw0, vw3, hw0, hw2, hw3);
    }

    // Wave(64) shuffle reduction.
#pragma unroll
    for (int off = 32; off > 0; off >>= 1) acc += __shfl_down(acc, off, 64);

    __shared__ float wsum[4];
    if (w == 0) wsum[tid >> 6] = acc;
    __syncthreads();
    if (tid == 0)
        partial[blockIdx.x] = (wsum[0] + wsum[1]) + (wsum[2] + wsum[3]);
}

__global__ __launch_bounds__(256) void tv_stage2(const float* __restrict__ partial,
                                                 float* __restrict__ out) {
    // 1024 partials = 256 x float4.
    const float4 p = ((const float4*)partial)[threadIdx.x];
    float acc = (p.x + p.y) + (p.z + p.w);
#pragma unroll
    for (int off = 32; off > 0; off >>= 1) acc += __shfl_down(acc, off, 64);
    __shared__ float wsum[4];
    if ((threadIdx.x & 63) == 0) wsum[threadIdx.x >> 6] = acc;
    __syncthreads();
    if (threadIdx.x == 0)
        out[0] = (wsum[0] + wsum[1]) + (wsum[2] + wsum[3]);  // pure overwrite
}

extern "C" void kernel_launch(void* const* d_in, const int* in_sizes, int n_in,
                              void* d_out, int out_size, void* d_ws, size_t ws_size,
                              hipStream_t stream) {
    const float* fai = (const float*)d_in[0];
    float* out = (float*)d_out;
    float* partial = (float*)d_ws;              // 1024 floats, fully overwritten

    const int n_blocks = 8192 / 8;              // 2 imgs/wave x 4 waves/block
    tv_stage1<<<n_blocks, 256, 0, stream>>>(fai, partial);
    tv_stage2<<<1, 256, 0, stream>>>(partial, out);
}